// Round 4
// baseline (530.854 us; speedup 1.0000x reference)
//
#include <hip/hip_runtime.h>
#include <math.h>

#define CH 128   // chunk rows (segment with n<=CH spans <=2 chunks)

// ---------------------------------------------------------------------------
// seg_starts[s] = first element index whose map value >= s (map sorted)
// ---------------------------------------------------------------------------
__global__ void k_segstarts(const int* __restrict__ map, int* __restrict__ starts,
                            int V, int S) {
    int i = blockIdx.x * blockDim.x + threadIdx.x;
    if (i >= V) return;
    int cur  = map[i];
    int prev = (i == 0) ? -1 : map[i - 1];
    for (int s = prev + 1; s <= cur; ++s) starts[s] = i;
    if (i == V - 1) {
        for (int s = cur + 1; s <= S; ++s) starts[s] = V;
    }
}

// M[i][j] = sum_h Wk[h][i]*Wv[h][j] ;  Wt[i][o] = Wo[o][i]
__global__ void k_prep(const float* __restrict__ Wk, const float* __restrict__ Wv,
                       const float* __restrict__ Wo,
                       float* __restrict__ M, float* __restrict__ Wt) {
    int i = blockIdx.x;
    int j = threadIdx.x;
    float acc = 0.f;
#pragma unroll 8
    for (int h = 0; h < 128; ++h)
        acc += Wk[h * 128 + i] * Wv[h * 128 + j];
    M[i * 128 + j]  = acc;
    Wt[i * 128 + j] = Wo[j * 128 + i];
}

// ---------------------------------------------------------------------------
// p1: segment SUMS via flat chunk streaming. Block=256 thr = 2 chunks of 128
// rows; thread owns one column, walks its chunk's rows (coalesced 256B/wave).
// Partial flush: A-slot if segment starts in this chunk, else B-slot.
// Zero-flush skipped segments so every (A/B) slot a consumer reads is written.
// Segments with n>CH are skipped (k_fix1 recomputes them fully into A).
// ---------------------------------------------------------------------------
__global__ __launch_bounds__(256) void k_p1(const float* __restrict__ E,
        const int* __restrict__ map, const int* __restrict__ starts,
        float* __restrict__ meanA, float* __restrict__ meanB, int V) {
    const int t  = threadIdx.x;
    const int R0 = blockIdx.x * 256 + (t >> 7) * CH;
    if (R0 >= V) return;
    const int nr = min(CH, V - R0);
    const int c  = t & 127;
    const float* Ec = E + (size_t)R0 * 128 + c;
    const int* mp = map + R0;

#define P1_FLUSH(SS, VAL) do { \
        int st_ = starts[(SS)]; int n_ = starts[(SS) + 1] - st_; \
        if (n_ <= CH) { \
            float* d_ = (st_ >= R0) ? meanA : meanB; \
            d_[(size_t)(SS) * 128 + c] = (VAL); } } while (0)

    float acc = 0.f;
    int cur = mp[0];
    int r = 0;
    for (; r + 8 <= nr; r += 8) {
        float v0 = Ec[(size_t)(r+0)*128]; float v1 = Ec[(size_t)(r+1)*128];
        float v2 = Ec[(size_t)(r+2)*128]; float v3 = Ec[(size_t)(r+3)*128];
        float v4 = Ec[(size_t)(r+4)*128]; float v5 = Ec[(size_t)(r+5)*128];
        float v6 = Ec[(size_t)(r+6)*128]; float v7 = Ec[(size_t)(r+7)*128];
        int m0=mp[r+0], m1=mp[r+1], m2=mp[r+2], m3=mp[r+3];
        int m4=mp[r+4], m5=mp[r+5], m6=mp[r+6], m7=mp[r+7];
#define P1_STEP(MM, VV) do { \
        if ((MM) != cur) { P1_FLUSH(cur, acc); \
            for (int ss_ = cur + 1; ss_ < (MM); ++ss_) P1_FLUSH(ss_, 0.f); \
            cur = (MM); acc = 0.f; } \
        acc += (VV); } while (0)
        P1_STEP(m0, v0); P1_STEP(m1, v1); P1_STEP(m2, v2); P1_STEP(m3, v3);
        P1_STEP(m4, v4); P1_STEP(m5, v5); P1_STEP(m6, v6); P1_STEP(m7, v7);
    }
    for (; r < nr; ++r) {
        float v = Ec[(size_t)r * 128];
        int m = mp[r];
        P1_STEP(m, v);
    }
    P1_FLUSH(cur, acc);   // cur == seg of last row; no trailing gaps in p1
#undef P1_STEP
#undef P1_FLUSH
}

// Fixup for n>CH segments: full column sums -> A slot (B never read for n>CH).
__global__ __launch_bounds__(256) void k_fix1(const float* __restrict__ E,
        const int* __restrict__ starts, float* __restrict__ meanA, int S) {
    const int seg  = blockIdx.x * 4 + (threadIdx.x >> 6);
    const int lane = threadIdx.x & 63;
    if (seg >= S) return;
    const int r0 = starts[seg], n = starts[seg + 1] - r0;
    if (n <= CH) return;
    const float* p = E + (size_t)r0 * 128 + 2 * lane;
    float a0 = 0.f, a1 = 0.f;
    for (int r = 0; r < n; ++r) {
        const float2 e = *(const float2*)(p + (size_t)r * 128);
        a0 += e.x; a1 += e.y;
    }
    meanA[(size_t)seg * 128 + 2 * lane]     = a0;
    meanA[(size_t)seg * 128 + 2 * lane + 1] = a1;
}

// ebar = (A + B?)/n
__global__ __launch_bounds__(256) void k_combine1(const float* __restrict__ meanA,
        const float* __restrict__ meanB, const int* __restrict__ starts,
        float* __restrict__ ebar, int S) {
    const int idx = blockIdx.x * 256 + threadIdx.x;
    const int s = idx >> 5, qd = idx & 31;
    if (s >= S) return;
    const int st = starts[s], n = starts[s + 1] - st;
    float4 v = make_float4(0.f, 0.f, 0.f, 0.f);
    if (n > 0) {
        const size_t o = (size_t)s * 128 + qd * 4;
        v = *(const float4*)(meanA + o);
        const bool spans = (st >> 7) != ((st + n - 1) >> 7);
        if (spans && n <= CH) {
            const float4 b = *(const float4*)(meanB + o);
            v.x += b.x; v.y += b.y; v.z += b.z; v.w += b.w;
        }
        const float inv = 1.0f / (float)n;
        v.x *= inv; v.y *= inv; v.z *= inv; v.w *= inv;
    }
    *(float4*)(ebar + (size_t)s * 128 + qd * 4) = v;
}

// q[s][j] = sum_i ebar[s][i] * M[i][j]
__global__ __launch_bounds__(256) void k_q(const float* __restrict__ ebar,
                                           const float* __restrict__ M,
                                           float* __restrict__ q, int S) {
    const int j  = threadIdx.x & 127;
    const int g  = threadIdx.x >> 7;
    const int s0 = blockIdx.x * 8 + g * 4;
    const float* e0 = ebar + (size_t)min(s0 + 0, S - 1) * 128;
    const float* e1 = ebar + (size_t)min(s0 + 1, S - 1) * 128;
    const float* e2 = ebar + (size_t)min(s0 + 2, S - 1) * 128;
    const float* e3 = ebar + (size_t)min(s0 + 3, S - 1) * 128;
    float q0 = 0.f, q1 = 0.f, q2 = 0.f, q3 = 0.f;
#pragma unroll 8
    for (int i = 0; i < 128; ++i) {
        const float m = M[i * 128 + j];
        q0 += m * e0[i]; q1 += m * e1[i]; q2 += m * e2[i]; q3 += m * e3[i];
    }
    if (s0 + 0 < S) q[(size_t)(s0 + 0) * 128 + j] = q0;
    if (s0 + 1 < S) q[(size_t)(s0 + 1) * 128 + j] = q1;
    if (s0 + 2 < S) q[(size_t)(s0 + 2) * 128 + j] = q2;
    if (s0 + 3 < S) q[(size_t)(s0 + 3) * 128 + j] = q3;
}

// ---------------------------------------------------------------------------
// p3: fused scores + exp + weighted sums, ONE flat pass over E.
// Wave per 128-row chunk (4 waves/block, wave-autonomous, no barriers).
// Lane: c = col-quad 0..31, g = row stride 0/1. Per 32-row subtile:
//   A) load 16 float4/thread (rows 2k+g), partial dot vs q -> LDS pscore
//   B) lanes<32 reduce 32 partials -> w = exp(score) -> LDS
//   C) Y4 += w * (E4 kept in registers), Z += w; flush per segment to A/B
//      slots (strided by g), zero-flushing skipped segments.
// No max-shift: |score| <~ 20 here, exp is fp32-safe, matches reference math.
// ---------------------------------------------------------------------------
__global__ __launch_bounds__(256) void k_p3(const float* __restrict__ E,
        const int* __restrict__ map, const int* __restrict__ starts,
        const float* __restrict__ q,
        float* __restrict__ Y,     // [ab*2+g][S][128]
        float* __restrict__ Z,     // [ab*2+g][S]
        int V, int S) {
    __shared__ float psc[4][32][34];
    __shared__ float wls[4][32];
    const int t    = threadIdx.x;
    const int wv   = t >> 6;
    const int lane = t & 63;
    const int R0   = (blockIdx.x * 4 + wv) * CH;
    if (R0 >= V) return;
    const int nr = min(CH, V - R0);
    const int c  = lane & 31;
    const int g  = lane >> 5;
    const int* mp = map + R0;
    const float* Eb = E + (size_t)R0 * 128 + c * 4;

#define P3_FLUSH(SS, Y4, ZV) do { \
        int st_ = starts[(SS)]; int n_ = starts[(SS) + 1] - st_; \
        if (n_ <= CH) { \
            int k_ = ((st_ >= R0) ? 0 : 2) + g; \
            float* yd_ = Y + ((size_t)k_ * S + (SS)) * 128 + c * 4; \
            yd_[0] = (Y4).x; yd_[1] = (Y4).y; yd_[2] = (Y4).z; yd_[3] = (Y4).w; \
            if (c == 0) Z[(size_t)k_ * S + (SS)] = (ZV); } } while (0)

    const float4 f4z = make_float4(0.f, 0.f, 0.f, 0.f);
    float4 accY = f4z;
    float accZ = 0.f;
    int cur = mp[0];
    int qs = -1;
    float4 qv = f4z;

    for (int sub = 0; sub < 4; ++sub) {
        const int base = sub * 32;
        float4 ev[16];
        // ---- A: load + partial dot -> LDS ----
#pragma unroll
        for (int kk = 0; kk < 16; ++kk) {
            const int lr = 2 * kk + g;
            const int r  = base + lr;
            if (r < nr) {
                ev[kk] = *(const float4*)(Eb + (size_t)r * 128);
                const int s_ = mp[r];
                if (s_ != qs) {
                    qv = *(const float4*)(q + (size_t)s_ * 128 + c * 4);
                    qs = s_;
                }
                psc[wv][c][lr] = ev[kk].x * qv.x + ev[kk].y * qv.y
                               + ev[kk].z * qv.z + ev[kk].w * qv.w;
            }
        }
        // ---- B: reduce + exp (lanes 0..31); same-wave LDS ordering ----
        if (lane < 32 && base + lane < nr) {
            float s0 = 0.f, s1 = 0.f, s2 = 0.f, s3 = 0.f;
#pragma unroll
            for (int i = 0; i < 32; i += 4) {
                s0 += psc[wv][i + 0][lane];
                s1 += psc[wv][i + 1][lane];
                s2 += psc[wv][i + 2][lane];
                s3 += psc[wv][i + 3][lane];
            }
            wls[wv][lane] = __expf(s0 + s1 + s2 + s3);
        }
        // ---- C: weighted accumulation + segment flushes ----
#pragma unroll
        for (int kk = 0; kk < 16; ++kk) {
            const int lr = 2 * kk + g;
            const int r  = base + lr;
            if (r < nr) {
                const float wk = wls[wv][lr];
                const int s_ = mp[r];
                if (s_ != cur) {
                    P3_FLUSH(cur, accY, accZ);
                    for (int ss_ = cur + 1; ss_ < s_; ++ss_) P3_FLUSH(ss_, f4z, 0.f);
                    cur = s_; accY = f4z; accZ = 0.f;
                }
                accY.x += wk * ev[kk].x; accY.y += wk * ev[kk].y;
                accY.z += wk * ev[kk].z; accY.w += wk * ev[kk].w;
                accZ += wk;
            }
        }
    }
    P3_FLUSH(cur, accY, accZ);
    const int lastseg = mp[nr - 1];
    for (int ss = cur + 1; ss <= lastseg; ++ss) P3_FLUSH(ss, f4z, 0.f);
#undef P3_FLUSH
}

// Fixup for n>CH segments: full scores+exp+sums -> (ab=0,g=0) slot; g=1 zeroed.
__global__ __launch_bounds__(256) void k_fix3(const float* __restrict__ E,
        const int* __restrict__ starts, const float* __restrict__ q,
        float* __restrict__ Y, float* __restrict__ Z, int S) {
    const int seg  = blockIdx.x * 4 + (threadIdx.x >> 6);
    const int lane = threadIdx.x & 63;
    if (seg >= S) return;
    const int r0 = starts[seg], n = starts[seg + 1] - r0;
    if (n <= CH) return;
    const float* p = E + (size_t)r0 * 128 + 2 * lane;
    const float2 qv = *(const float2*)(q + (size_t)seg * 128 + 2 * lane);
    float y0 = 0.f, y1 = 0.f, z = 0.f;
    for (int r = 0; r < n; ++r) {
        const float2 e = *(const float2*)(p + (size_t)r * 128);
        float d = e.x * qv.x + e.y * qv.y;
        d += __shfl_xor(d, 1);  d += __shfl_xor(d, 2);  d += __shfl_xor(d, 4);
        d += __shfl_xor(d, 8);  d += __shfl_xor(d, 16); d += __shfl_xor(d, 32);
        const float w = __expf(d);
        z += w; y0 += w * e.x; y1 += w * e.y;
    }
    float* yd0 = Y + (size_t)seg * 128 + 2 * lane;                      // slot 0
    float* yd1 = Y + ((size_t)1 * S + seg) * 128 + 2 * lane;            // slot 1
    yd0[0] = y0; yd0[1] = y1;
    yd1[0] = 0.f; yd1[1] = 0.f;
    if (lane == 0) { Z[seg] = z; Z[(size_t)S + seg] = 0.f; }
}

// ---------------------------------------------------------------------------
// k_out: combine Y/Z slots -> etilde (LDS), then out = etilde @ Wt.
// ---------------------------------------------------------------------------
__global__ __launch_bounds__(256) void k_out(const float* __restrict__ Wt,
        const float* __restrict__ Y, const float* __restrict__ Z,
        const int* __restrict__ starts, float* __restrict__ out, int S) {
    __shared__ float et[8][128];
    const int t  = threadIdx.x;
    const int sb = blockIdx.x * 8;
    {
        const int ls = t >> 5, qd = t & 31;
        const int s = sb + ls;
        float4 v = make_float4(0.f, 0.f, 0.f, 0.f);
        if (s < S) {
            const int st = starts[s], n = starts[s + 1] - st;
            if (n > 0) {
                const size_t o = (size_t)s * 128 + qd * 4;
                const float4 a0 = *(const float4*)(Y + o);
                const float4 a1 = *(const float4*)(Y + (size_t)1 * S * 128 + o);
                float z = Z[s] + Z[(size_t)S + s];
                v.x = a0.x + a1.x; v.y = a0.y + a1.y;
                v.z = a0.z + a1.z; v.w = a0.w + a1.w;
                const bool spans = (st >> 7) != ((st + n - 1) >> 7);
                if (spans && n <= CH) {
                    const float4 b0 = *(const float4*)(Y + (size_t)2 * S * 128 + o);
                    const float4 b1 = *(const float4*)(Y + (size_t)3 * S * 128 + o);
                    v.x += b0.x + b1.x; v.y += b0.y + b1.y;
                    v.z += b0.z + b1.z; v.w += b0.w + b1.w;
                    z += Z[(size_t)2 * S + s] + Z[(size_t)3 * S + s];
                }
                const float iz = 1.0f / z;
                v.x *= iz; v.y *= iz; v.z *= iz; v.w *= iz;
            }
        }
        *(float4*)&et[ls][qd * 4] = v;
    }
    __syncthreads();
    const int j = t & 127, g = t >> 7;
    float o0 = 0.f, o1 = 0.f, o2 = 0.f, o3 = 0.f;
#pragma unroll 8
    for (int i = 0; i < 128; ++i) {
        const float w = Wt[i * 128 + j];
        o0 += w * et[g * 4 + 0][i];
        o1 += w * et[g * 4 + 1][i];
        o2 += w * et[g * 4 + 2][i];
        o3 += w * et[g * 4 + 3][i];
    }
    if (sb + g * 4 + 0 < S) out[(size_t)(sb + g * 4 + 0) * 128 + j] = o0;
    if (sb + g * 4 + 1 < S) out[(size_t)(sb + g * 4 + 1) * 128 + j] = o1;
    if (sb + g * 4 + 2 < S) out[(size_t)(sb + g * 4 + 2) * 128 + j] = o2;
    if (sb + g * 4 + 3 < S) out[(size_t)(sb + g * 4 + 3) * 128 + j] = o3;
}

// ---------------------------------------------------------------------------
extern "C" void kernel_launch(void* const* d_in, const int* in_sizes, int n_in,
                              void* d_out, int out_size, void* d_ws, size_t ws_size,
                              hipStream_t stream) {
    const float* E   = (const float*)d_in[0];
    const int*   map = (const int*)d_in[1];
    const float* Wk  = (const float*)d_in[3];
    const float* Wv  = (const float*)d_in[4];
    const float* Wo  = (const float*)d_in[5];
    float* out = (float*)d_out;

    const int V = in_sizes[1];
    const int S = out_size / 128;

    char* p = (char*)d_ws;
    auto alloc = [&](size_t bytes) {
        char* r = p;
        p += (bytes + 255) & ~(size_t)255;
        return r;
    };
    int*   starts = (int*)alloc((size_t)(S + 1) * sizeof(int));
    float* M      = (float*)alloc(128 * 128 * sizeof(float));
    float* Wt     = (float*)alloc(128 * 128 * sizeof(float));
    float* ebar   = (float*)alloc((size_t)S * 128 * sizeof(float));
    float* q      = (float*)alloc((size_t)S * 128 * sizeof(float));
    float* meanA  = (float*)alloc((size_t)S * 128 * sizeof(float));
    float* meanB  = (float*)alloc((size_t)S * 128 * sizeof(float));
    float* Y      = (float*)alloc((size_t)4 * S * 128 * sizeof(float));
    float* Z      = (float*)alloc((size_t)4 * S * sizeof(float));

    k_segstarts<<<(V + 255) / 256, 256, 0, stream>>>(map, starts, V, S);
    k_prep<<<128, 128, 0, stream>>>(Wk, Wv, Wo, M, Wt);
    k_p1<<<(V + 255) / 256, 256, 0, stream>>>(E, map, starts, meanA, meanB, V);
    k_fix1<<<(S + 3) / 4, 256, 0, stream>>>(E, starts, meanA, S);
    k_combine1<<<(S * 32 + 255) / 256, 256, 0, stream>>>(meanA, meanB, starts, ebar, S);
    k_q<<<(S + 7) / 8, 256, 0, stream>>>(ebar, M, q, S);
    k_p3<<<(V + 511) / 512, 256, 0, stream>>>(E, map, starts, q, Y, Z, V, S);
    k_fix3<<<(S + 3) / 4, 256, 0, stream>>>(E, starts, q, Y, Z, S);
    k_out<<<(S + 7) / 8, 256, 0, stream>>>(Wt, Y, Z, starts, out, S);
}